// Round 1
// baseline (1289.036 us; speedup 1.0000x reference)
//
#include <hip/hip_runtime.h>
#include <math.h>

// Problem constants (from reference)
#define N_ROWS  500000
#define DIM     128
#define NNZ     262144
#define LR      0.001f
#define B1      0.9f
#define B2      0.999f
#define EPS     1e-8f

// float4 elements per row (128 floats / 4)
#define Q_PER_ROW   (DIM / 4)            // 32
#define TOTAL_Q     (N_ROWS * Q_PER_ROW) // 16,000,000

// ext_vector so __builtin_nontemporal_{load,store} accepts it directly
typedef float v4f __attribute__((ext_vector_type(4)));

// ---------------------------------------------------------------------------
// Kernel 1: scatter inverse map  inv[idx[i]] = i   (inv pre-set to -1 via
// hipMemsetAsync 0xFF). idx is effectively int32 (jax x64 disabled).
// ---------------------------------------------------------------------------
__global__ __launch_bounds__(256) void build_inv_kernel(
    const int* __restrict__ idx, int* __restrict__ inv)
{
    int i = blockIdx.x * blockDim.x + threadIdx.x;
    if (i < NNZ) {
        inv[idx[i]] = i;
    }
}

// ---------------------------------------------------------------------------
// Kernel 2: fused copy + sparse Adam update.
// Grid-stride (2048 blocks x 256 thr), ~30 independent iterations/thread for
// MLP; all six bulk streams are read-once/write-once -> nontemporal policy.
// Outputs: out[0 .. 16M)   = param_new   (in v4f units)
//          out[16M .. 32M) = m_new
//          out[32M .. 48M) = v_new
// ---------------------------------------------------------------------------
__global__ __launch_bounds__(256) void adam_fused_kernel(
    const v4f* __restrict__ param,
    const v4f* __restrict__ m,
    const v4f* __restrict__ v,
    const v4f* __restrict__ grad,
    const int* __restrict__ inv,
    v4f* __restrict__ out,
    float lr_t, float bc1, float bc2)
{
    const int stride = gridDim.x * blockDim.x;
    int tid = blockIdx.x * blockDim.x + threadIdx.x;

    #pragma unroll 2
    for (; tid < TOTAL_Q; tid += stride)
    {
        const int row  = tid >> 5;   // tid / 32
        const int quad = tid & 31;   // tid % 32

        // read-once streams: nontemporal (evict-first, keep L2 for inv)
        v4f p  = __builtin_nontemporal_load(&param[tid]);
        v4f mm = __builtin_nontemporal_load(&m[tid]);
        v4f vv = __builtin_nontemporal_load(&v[tid]);

        const int j = inv[row];      // cached: 2 MB table, wave-broadcast

        if (j >= 0) {
            v4f g = __builtin_nontemporal_load(&grad[j * Q_PER_ROW + quad]);

            // m_new = m + (1-b1)*(g - m)    (identical arithmetic to verified)
            mm.x += (1.0f - B1) * (g.x - mm.x);
            mm.y += (1.0f - B1) * (g.y - mm.y);
            mm.z += (1.0f - B1) * (g.z - mm.z);
            mm.w += (1.0f - B1) * (g.w - mm.w);

            // v_new = v + (1-b2)*(g*g - v)
            vv.x += (1.0f - B2) * (g.x * g.x - vv.x);
            vv.y += (1.0f - B2) * (g.y * g.y - vv.y);
            vv.z += (1.0f - B2) * (g.z * g.z - vv.z);
            vv.w += (1.0f - B2) * (g.w * g.w - vv.w);

            // hats + param update (divisions kept, same order as reference)
            float mtx = mm.x / bc1, mty = mm.y / bc1, mtz = mm.z / bc1, mtw = mm.w / bc1;
            float vtx = vv.x / bc2, vty = vv.y / bc2, vtz = vv.z / bc2, vtw = vv.w / bc2;

            p.x -= lr_t * mtx / (sqrtf(vtx) + EPS);
            p.y -= lr_t * mty / (sqrtf(vty) + EPS);
            p.z -= lr_t * mtz / (sqrtf(vtz) + EPS);
            p.w -= lr_t * mtw / (sqrtf(vtw) + EPS);
        }

        // write-once streams: nontemporal stores (no L2 pollution / RFO)
        __builtin_nontemporal_store(p,  &out[tid]);
        __builtin_nontemporal_store(mm, &out[tid + TOTAL_Q]);
        __builtin_nontemporal_store(vv, &out[tid + 2 * TOTAL_Q]);
    }
}

// ---------------------------------------------------------------------------
extern "C" void kernel_launch(void* const* d_in, const int* in_sizes, int n_in,
                              void* d_out, int out_size, void* d_ws, size_t ws_size,
                              hipStream_t stream)
{
    const float* param = (const float*)d_in[0];
    const float* m     = (const float*)d_in[1];
    const float* v     = (const float*)d_in[2];
    const float* grad  = (const float*)d_in[3];
    const int*   idx   = (const int*)d_in[4];

    int* inv = (int*)d_ws; // N_ROWS ints = 2 MB

    // Bias-correction scalars (ITERATION = 1), identical to verified version.
    double bc1d = 1.0 - (double)0.9;    // 0.1
    double bc2d = 1.0 - (double)0.999;  // 0.001
    float bc1 = (float)bc1d;
    float bc2 = (float)bc2d;
    float lr_t = LR * sqrtf(bc2) / bc1;

    // inv = -1 everywhere (0xFFFFFFFF)
    hipMemsetAsync(inv, 0xFF, (size_t)N_ROWS * sizeof(int), stream);

    // scatter inverse index map
    build_inv_kernel<<<(NNZ + 255) / 256, 256, 0, stream>>>(idx, inv);

    // fused copy + adam: capped grid + grid-stride (Guideline 11, memory-bound)
    adam_fused_kernel<<<2048, 256, 0, stream>>>(
        (const v4f*)param, (const v4f*)m, (const v4f*)v,
        (const v4f*)grad, inv, (v4f*)d_out, lr_t, bc1, bc2);
}